// Round 10
// baseline (230.776 us; speedup 1.0000x reference)
//
#include <hip/hip_runtime.h>

// InfoCNECauchy: loss = mean_r log(sum_{j!=r} sim[r,j]) - mean_r log(sim[r, r^4096])
// sim = t^2/(d2+t^2), d2 = ||f_r||^2 + ||f_c||^2 - 2<f_r,f_c>, t=0.07
//
// R10: LDS-free K-loop. Both MFMA operands' fragments are 16 contiguous
// bytes of an fbf row, so each lane loads them straight from global (L2)
// with global_load_dwordx4 -- no staging, no global_load_lds, and ZERO
// __syncthreads in the K-loop. R5's measured limiters (LDS pipe ~75% busy,
// 2 barrier drains/kt) are deleted wholesale; loads pipeline across kt with
// compiler vmcnt(N) (the AITER pattern). XCD banding keeps the panel
// working set L2-local (~1.8 TB/s per XCD demand vs 4.3 ceiling).
// Epilogue / triangular tiles / 3 nodes: R5 verbatim.

#define N2 8192
#define DIM 512
#define NT 64 /* 8192/128 tiles per dim */
#define NTILES (NT * (NT + 1) / 2)
#define T2 0.0049f

typedef float floatx4 __attribute__((ext_vector_type(4)));
typedef __bf16 bf16x8 __attribute__((ext_vector_type(8)));
typedef __bf16 bf16x4 __attribute__((ext_vector_type(4)));

// ---- prep: fp32 -> bf16 + row norms + zero rowsum ------------------------
__global__ __launch_bounds__(256) void prep_kernel(const float* __restrict__ f,
                                                   __bf16* __restrict__ fbf,
                                                   float* __restrict__ sq,
                                                   float* __restrict__ rowsum) {
  const int t = threadIdx.x;
  if (t < 2) rowsum[blockIdx.x * 2 + t] = 0.f;
  const int row = blockIdx.x * 2 + (t >> 7);
  const int ci = (t & 127) * 4;
  const float4 v = *(const float4*)(f + (size_t)row * DIM + ci);
  bf16x4 b;
  b[0] = (__bf16)v.x; b[1] = (__bf16)v.y; b[2] = (__bf16)v.z; b[3] = (__bf16)v.w;
  *(bf16x4*)(fbf + (size_t)row * DIM + ci) = b;
  float s = v.x * v.x + v.y * v.y + v.z * v.z + v.w * v.w;
#pragma unroll
  for (int off = 1; off < 64; off <<= 1) s += __shfl_xor(s, off, 64);
  __shared__ float red[4];
  if ((t & 63) == 0) red[t >> 6] = s;
  __syncthreads();
  if ((t & 127) == 0) sq[row] = red[t >> 6] + red[(t >> 6) + 1];
}

// ---- fused GEMM (upper triangle, XCD-banded, NO LDS) + Cauchy epilogue ---
__global__ __launch_bounds__(256) void gemm_kernel(const __bf16* __restrict__ fbf,
                                                   const float* __restrict__ sq,
                                                   float* __restrict__ rowsum,
                                                   float* __restrict__ spart) {
  // XCD-banded tile decode: x = blockIdx%8 (XCD), k = blockIdx/8 (0..259).
  int by, bx;
  {
    const int x = blockIdx.x & 7;
    int kk = blockIdx.x >> 3;
    int band = x;
    const int n1 = 250 - 16 * x;
    if (kk >= n1) { kk -= n1; band = 15 - x; }
    const int by0 = band * 4;
    int bxx = by0;
    int cnt;
    while (kk >= (cnt = min(4, bxx - by0 + 1))) { kk -= cnt; ++bxx; }
    by = by0 + kk;
    bx = bxx;
  }
  const int brow = by * 128;
  const int bcol = bx * 128;
  const bool diag = (by == bx);

  const int t = threadIdx.x;
  const int lane = t & 63;
  const int w = t >> 6;
  const int wrow = (w >> 1) * 64;
  const int wcol = (w & 1) * 64;
  const int q4 = lane >> 4;  // 0..3 -> k-chunk q4*8
  const int lc = lane & 15;  // 0..15 -> row/col within 16-block

  floatx4 acc[4][4] = {};

  // Per-lane fragment row pointers: A row (brow+wrow+mr*16+lc), B row
  // (bcol+wcol+mc*16+lc), both at k-offset q4*8. 16B-aligned.
  const __bf16* ap[4];
  const __bf16* bp[4];
#pragma unroll
  for (int mr = 0; mr < 4; ++mr)
    ap[mr] = fbf + (size_t)(brow + wrow + mr * 16 + lc) * DIM + q4 * 8;
#pragma unroll
  for (int mc = 0; mc < 4; ++mc)
    bp[mc] = fbf + (size_t)(bcol + wcol + mc * 16 + lc) * DIM + q4 * 8;

#pragma unroll 2
  for (int kt = 0; kt < DIM / 32; ++kt) {
    const int k0 = kt * 32;
    bf16x8 af[4], bfr[4];
#pragma unroll
    for (int mr = 0; mr < 4; ++mr) af[mr] = *(const bf16x8*)(ap[mr] + k0);
#pragma unroll
    for (int mc = 0; mc < 4; ++mc) bfr[mc] = *(const bf16x8*)(bp[mc] + k0);
#pragma unroll
    for (int mr = 0; mr < 4; ++mr)
#pragma unroll
      for (int mc = 0; mc < 4; ++mc)
        acc[mr][mc] =
            __builtin_amdgcn_mfma_f32_16x16x32_bf16(af[mr], bfr[mc], acc[mr][mc], 0, 0, 0);
  }

  // Epilogue (R5 verbatim). C/D layout: col = lane&15, row = (lane>>4)*4+reg.
  float sqc[4];
#pragma unroll
  for (int mc = 0; mc < 4; ++mc) sqc[mc] = sq[bcol + wcol + mc * 16 + lc];

  float cs[4] = {0.f, 0.f, 0.f, 0.f};  // column partial sums (off-diag tiles)

#pragma unroll
  for (int mr = 0; mr < 4; ++mr) {
#pragma unroll
    for (int reg = 0; reg < 4; ++reg) {
      const int r = brow + wrow + mr * 16 + q4 * 4 + reg;
      const float sr = sq[r];
      const int pc = r ^ (N2 / 2);
      float rs = 0.f;
#pragma unroll
      for (int mc = 0; mc < 4; ++mc) {
        const int c = bcol + wcol + mc * 16 + lc;
        const float g = acc[mr][mc][reg];
        const float d2 = fmaxf(sr + sqc[mc] - 2.f * g, 0.f);
        const float s = T2 * __builtin_amdgcn_rcpf(d2 + T2);
        if (c != r) rs += s;  // diagonal excluded exactly (diag tiles only)
        cs[mc] += s;          // unused on diag tiles
        if (c == pc) { spart[r] = s; spart[pc] = s; }  // off-diag only, 1 lane
      }
#pragma unroll
      for (int off = 1; off < 16; off <<= 1) rs += __shfl_xor(rs, off, 64);
      if (lc == 0) atomicAdd(&rowsum[r], rs);
    }
  }

  if (!diag) {
#pragma unroll
    for (int mc = 0; mc < 4; ++mc) {
      float v = cs[mc];
      v += __shfl_xor(v, 16, 64);
      v += __shfl_xor(v, 32, 64);
      if (lane < 16) atomicAdd(&rowsum[bcol + wcol + mc * 16 + lane], v);
    }
  }
}

// ---- final scalar reduction ---------------------------------------------
__global__ __launch_bounds__(256) void final_kernel(const float* __restrict__ rowsum,
                                                    const float* __restrict__ spart,
                                                    float* __restrict__ out) {
  const int t = threadIdx.x;
  float a = 0.f;
  for (int r = t; r < N2; r += 256) a += logf(rowsum[r]) - logf(spart[r]);
#pragma unroll
  for (int off = 1; off < 64; off <<= 1) a += __shfl_xor(a, off, 64);
  __shared__ float red[4];
  if ((t & 63) == 0) red[t >> 6] = a;
  __syncthreads();
  if (t == 0) out[0] = (red[0] + red[1] + red[2] + red[3]) * (1.0f / (float)N2);
}

extern "C" void kernel_launch(void* const* d_in, const int* in_sizes, int n_in,
                              void* d_out, int out_size, void* d_ws, size_t ws_size,
                              hipStream_t stream) {
  const float* features = (const float*)d_in[0];
  float* out = (float*)d_out;

  char* ws = (char*)d_ws;
  __bf16* fbf = (__bf16*)ws;                                     // 8 MB
  float* sq = (float*)(ws + (size_t)N2 * DIM * sizeof(__bf16));  // 32 KB
  float* rowsum = sq + N2;                                       // 32 KB
  float* spart = rowsum + N2;                                    // 32 KB

  prep_kernel<<<N2 / 2, 256, 0, stream>>>(features, fbf, sq, rowsum);
  gemm_kernel<<<NTILES, 256, 0, stream>>>(fbf, sq, rowsum, spart);
  final_kernel<<<1, 256, 0, stream>>>(rowsum, spart, out);
}